// Round 9
// baseline (577.274 us; speedup 1.0000x reference)
//
#include <hip/hip_runtime.h>
#include <stdint.h>

// Attention_48945447306134 on MI355X.
//   GEMM1: QKV = xb @ [wq*C|wk|wv]^T  (wq pre-scaled by softmax_scale*log2e)
//   RoPE in place; V pre-transposed to Vt[b][hk][d][s]
//   Flash attention, TRANSPOSED algebra: S^T = K Q^T, O^T = V^T P^T
//   This rev: (a) GEMM 3-stage pipeline -- counted s_waitcnt vmcnt(4) keeps
//   the newest tile's loads in flight across the barrier (cover ~2 K-steps),
//   paired-row LDS layout unchanged; (b) attn XCD swizzle REVERTED (r8 A/B:
//   +10.5 us regression -- attn is not HBM-bound, and co-locating blocks
//   that read the same K/V on one XCD contends in L2). GEMM swizzle kept.
//   GEMM2: out = attn @ woT (fp32 out)

typedef unsigned short u16;
typedef __bf16 bf16x8 __attribute__((ext_vector_type(8)));
typedef float  f32x4  __attribute__((ext_vector_type(4)));
typedef unsigned int u32x2 __attribute__((ext_vector_type(2)));

#define GLOAD16(gp, lp)                                                        \
  __builtin_amdgcn_global_load_lds(                                            \
      (const __attribute__((address_space(1))) void*)(gp),                     \
      (__attribute__((address_space(3))) void*)(lp), 16, 0, 0)

__device__ __forceinline__ u16 f2b(float f) {  // RNE f32->bf16
  union { float f; uint32_t u; } v; v.f = f;
  uint32_t r = v.u + 0x7FFFu + ((v.u >> 16) & 1u);
  return (u16)(r >> 16);
}
__device__ __forceinline__ float b2f(u16 h) {
  union { uint32_t u; float f; } v; v.u = ((uint32_t)h) << 16;
  return v.f;
}
// RNE pack via HW instruction
__device__ __forceinline__ uint2 pack4(float a, float b, float c, float d) {
  uint2 r;
  asm("v_cvt_pk_bf16_f32 %0, %1, %2" : "=v"(r.x) : "v"(a), "v"(b));
  asm("v_cvt_pk_bf16_f32 %0, %1, %2" : "=v"(r.y) : "v"(c), "v"(d));
  return r;
}

// block barrier that does NOT drain vmcnt (keeps staging loads in flight).
__device__ __forceinline__ void bar_sync() {
  asm volatile("s_waitcnt lgkmcnt(0)" ::: "memory");
  __builtin_amdgcn_s_barrier();
  asm volatile("" ::: "memory");
}

// ---------------- cast x -> bf16 ----------------
__global__ __launch_bounds__(256) void cast_x_kernel(const float4* __restrict__ in,
                                                     ushort4* __restrict__ out) {
  int i = blockIdx.x * 256 + threadIdx.x;
  float4 v = in[i];
  ushort4 o;
  o.x = f2b(v.x); o.y = f2b(v.y); o.z = f2b(v.z); o.w = f2b(v.w);
  out[i] = o;
}

// ------------- cast + transpose weight: W (KxN f32) -> WT (NxK bf16), * scale -------------
__global__ __launch_bounds__(256) void wtrans_kernel(const float* __restrict__ W,
                                                     u16* __restrict__ WT,
                                                     int K, int N, float scale) {
  __shared__ float t[32][33];
  int n0 = blockIdx.x * 32, k0 = blockIdx.y * 32;
  int tx = threadIdx.x, ty = threadIdx.y;  // 32 x 8
  for (int r = 0; r < 4; r++)
    t[ty + r * 8][tx] = W[(size_t)(k0 + ty + r * 8) * N + n0 + tx];
  __syncthreads();
  for (int r = 0; r < 4; r++)
    WT[(size_t)(n0 + ty + r * 8) * K + k0 + tx] = f2b(t[tx][ty + r * 8] * scale);
}

// ---------------- GEMM: C(MxN) = A(MxK) * BT(NxK)^T ----------------
// 128x128 tile, BK=32, 3-stage LDS pipeline (48 KB), counted vmcnt:
// per step wait vmcnt(4) (oldest tile's 4 loads land; the 4 newer keep
// flying), barrier, stage tile t+2 into buffer (cur+2)%3, compute tile t.
// Requires nt % 3 == 1 (nt = K/32 = 64 at both call sites).
// LDS layout: paired rows -- logical row r, 16B-chunk q stored at
//   u16 idx = (r>>1)*64 + (r&1)*32 + (q^((r>>1)&3))*8
// staged via pre-swizzled global source so the linear gload_lds dest lands
// exactly on it; frag reads hit 8 distinct bank-groups per 8 lanes (b128 min).
#define KSTEP(CUR, TT)                                                         \
  {                                                                            \
    if ((TT) + 1 < nt) asm volatile("s_waitcnt vmcnt(4)" ::: "memory");        \
    else               asm volatile("s_waitcnt vmcnt(0)" ::: "memory");        \
    bar_sync();                                                                \
    if ((TT) + 2 < nt) {                                                       \
      const size_t k0 = (size_t)((TT) + 2) * 32;                               \
      GLOAD16(Ag + k0, &As[((CUR) + 2) % 3][ldst]);                            \
      GLOAD16(Ag + k0 + (size_t)16 * K, &As[((CUR) + 2) % 3][ldst + 512]);     \
      GLOAD16(Bg + k0, &Bs[((CUR) + 2) % 3][ldst]);                            \
      GLOAD16(Bg + k0 + (size_t)16 * K, &Bs[((CUR) + 2) % 3][ldst + 512]);     \
    }                                                                          \
    bf16x8 af[4], bf[4];                                                       \
    for (int i = 0; i < 4; i++)                                                \
      af[i] = *(const bf16x8*)&As[CUR][wm * 32 + i * 512 + lrd];               \
    for (int i = 0; i < 4; i++)                                                \
      bf[i] = *(const bf16x8*)&Bs[CUR][wn * 32 + i * 512 + lrd];               \
    __builtin_amdgcn_s_setprio(1);                                             \
    for (int mi = 0; mi < 4; mi++)                                             \
      for (int ni = 0; ni < 4; ni++)                                           \
        acc[mi][ni] = __builtin_amdgcn_mfma_f32_16x16x32_bf16(                 \
            af[mi], bf[ni], acc[mi][ni], 0, 0, 0);                             \
    __builtin_amdgcn_s_setprio(0);                                             \
  }

template <bool BF16OUT>
__global__ __launch_bounds__(256) void gemm_bt_kernel(const u16* __restrict__ A,
                                                      const u16* __restrict__ BT,
                                                      void* __restrict__ Cv,
                                                      int K, int N) {
  __shared__ u16 As[3][64 * 64];
  __shared__ u16 Bs[3][64 * 64];
  const int tid = threadIdx.x;
  const int wave = tid >> 6, lane = tid & 63;
  const int quad = lane >> 4, l16 = lane & 15;
  const int wm = (wave >> 1) * 64, wn = (wave & 1) * 64;

  // XCD-aware bijective block swizzle (nwg % 8 == 0 for both call sites)
  const int nbx = gridDim.x;
  const int nwg = nbx * gridDim.y;
  const int d = blockIdx.x + blockIdx.y * nbx;
  const int w = (d & 7) * (nwg >> 3) + (d >> 3);
  const size_t m0 = (size_t)(w / nbx) * 128, n0 = (size_t)(w % nbx) * 128;

  f32x4 acc[4][4] = {};
  const int srow = wave * 32 + ((lane >> 3) << 1) + ((lane >> 2) & 1);
  const int tcol = ((lane & 3) ^ ((lane >> 3) & 3)) * 8;
  const u16* Ag = A + (m0 + srow) * (size_t)K + tcol;
  const u16* Bg = BT + (n0 + srow) * (size_t)K + tcol;
  const int ldst = wave * 1024;  // u16; per-instr +512 (16 rows)
  const int lrd = (l16 >> 1) * 64 + (l16 & 1) * 32 +
                  ((quad ^ ((l16 >> 1) & 3)) << 3);
  const int nt = K >> 5;  // must be ≡ 1 (mod 3); 64 at both call sites

  // prologue: stage tiles 0 and 1
  GLOAD16(Ag, &As[0][ldst]);
  GLOAD16(Ag + (size_t)16 * K, &As[0][ldst + 512]);
  GLOAD16(Bg, &Bs[0][ldst]);
  GLOAD16(Bg + (size_t)16 * K, &Bs[0][ldst + 512]);
  GLOAD16(Ag + 32, &As[1][ldst]);
  GLOAD16(Ag + 32 + (size_t)16 * K, &As[1][ldst + 512]);
  GLOAD16(Bg + 32, &Bs[1][ldst]);
  GLOAD16(Bg + 32 + (size_t)16 * K, &Bs[1][ldst + 512]);

  int t = 0;
  for (; t + 4 < nt; t += 3) {
    KSTEP(0, t);
    KSTEP(1, t + 1);
    KSTEP(2, t + 2);
  }
  // tail for nt % 3 == 1 (t == nt-4 here)
  KSTEP(0, t);
  KSTEP(1, t + 1);
  KSTEP(2, t + 2);
  KSTEP(0, t + 3);

  for (int mi = 0; mi < 4; mi++)
    for (int ni = 0; ni < 4; ni++)
      for (int r = 0; r < 4; r++) {
        size_t row = m0 + wm + mi * 16 + quad * 4 + r;
        size_t col = n0 + wn + ni * 16 + l16;
        if (BF16OUT) ((u16*)Cv)[row * N + col] = f2b(acc[mi][ni][r]);
        else         ((float*)Cv)[row * N + col] = acc[mi][ni][r];
      }
}

// ---------------- RoPE in place on QKV cols [0,2560) ----------------
__global__ __launch_bounds__(256) void rope_kernel(u16* __restrict__ QKV,
                                                   const float* __restrict__ cs,
                                                   const float* __restrict__ sn) {
  int tid = blockIdx.x * 256 + threadIdx.x;
  int row = tid / 1280;
  int p = tid - row * 1280;
  int s = row & 2047;
  int head = p >> 6, i = p & 63;
  u16* ptr = QKV + (size_t)row * 3072 + head * 128 + i * 2;
  unsigned int v = *(unsigned int*)ptr;
  float x0 = b2f((u16)(v & 0xffff)), x1 = b2f((u16)(v >> 16));
  float c = cs[s * 64 + i], ss = sn[s * 64 + i];
  u16 o0 = f2b(x0 * c - x1 * ss);
  u16 o1 = f2b(x0 * ss + x1 * c);
  *(unsigned int*)ptr = (unsigned int)o0 | ((unsigned int)o1 << 16);
}

// ---------------- V transpose ----------------
__global__ __launch_bounds__(256) void vtrans_kernel(const u16* __restrict__ QKV,
                                                     u16* __restrict__ Vt) {
  __shared__ u16 t[32][33];
  int b = blockIdx.z >> 2, hk = blockIdx.z & 3;
  int s0 = blockIdx.x * 32, d0 = blockIdx.y * 32;
  int tx = threadIdx.x, ty = threadIdx.y;
  const u16* src = QKV + (size_t)(b * 2048 + s0) * 3072 + 2560 + hk * 128 + d0;
  for (int r = 0; r < 4; r++)
    t[ty + r * 8][tx] = src[(size_t)(ty + r * 8) * 3072 + tx];
  __syncthreads();
  u16* dst = Vt + ((size_t)((b * 4 + hk) * 128 + d0)) * 2048 + s0;
  for (int r = 0; r < 4; r++)
    dst[(size_t)(ty + r * 8) * 2048 + tx] = t[tx][ty + r * 8];
}

// ---------------- flash attention (transposed algebra, P in registers) ------
// grid (qt=16, h=16, b=4), 256 threads = 4 waves, 32 q-rows/wave. Linear
// block mapping (XCD swizzle reverted -- r8 A/B showed +10.5us regression).
// Per iter kt:
//   [top] if kt>0: issue V_kt gload_lds
//   QK^T -> BARRIER_A -> issue K_{kt+1} gload_lds
//   softmax + exp->bf16 pack -> permlane32_swap/xor16 exchange -> pf (in-reg)
//   BARRIER_B: vmcnt(8) (drain V_kt, keep K flying)
//   PV -> BARRIER_END: vmcnt(0)
__global__ __launch_bounds__(256, 2) void attn_kernel(const u16* __restrict__ QKV,
                                                      const u16* __restrict__ Vt,
                                                      u16* __restrict__ AO) {
  __shared__ u16 KP[128 * 128];
  __shared__ u16 Vls[128 * 128];
  const int tid = threadIdx.x;
  const int wave = tid >> 6, lane = tid & 63;
  const int quad = lane >> 4, l16 = lane & 15;
  const int qt = blockIdx.x, h = blockIdx.y, b = blockIdx.z;
  const int hk = h >> 2;
  const int sw = l16 & 7;  // row-dependent swizzle key for this lane's rows

  // Q fragments (B-operand: n=q=l16, k=d)
  bf16x8 qf[2][4];
  {
    const u16* Qb = QKV + (size_t)(b * 2048 + qt * 128 + wave * 32) * 3072 + h * 128;
    for (int qb = 0; qb < 2; qb++)
      for (int ki = 0; ki < 4; ki++)
        qf[qb][ki] = *(const bf16x8*)(Qb + (size_t)(qb * 16 + l16) * 3072 + ki * 32 + quad * 8);
  }
  f32x4 o[8][2] = {};            // O^T: [db][qb], col=q(l16), row=d(quad*4+r)
  float m_[2] = {-1e30f, -1e30f}, l_[2] = {0.f, 0.f};

  const u16* Kg0 = QKV + 2048 + hk * 128;
  const u16* Vg0 = Vt + (size_t)((b * 4 + hk) * 128) * 2048;
  const int r4 = lane >> 4, c16 = lane & 15;

  // staging: tile t of K (rows=key, cols=d) / V (rows=d, cols=key), 8 chunks/wave
  auto stageK = [&](int t) {
    const u16* Kg = Kg0 + (size_t)(b * 2048 + t * 128) * 3072;
    for (int i = 0; i < 8; i++) {
      int grp = i * 4 + wave;
      int row = grp * 4 + r4;
      int ch = c16 ^ (row & 7);
      GLOAD16(Kg + (size_t)row * 3072 + ch * 8, &KP[grp * 512]);
    }
  };
  auto stageV = [&](int t) {
    const u16* Vg = Vg0 + t * 128;
    for (int i = 0; i < 8; i++) {
      int grp = i * 4 + wave;
      int row = grp * 4 + r4;
      int ch = c16 ^ (row & 7);
      GLOAD16(Vg + (size_t)row * 2048 + ch * 8, &Vls[grp * 512]);
    }
  };

  // ---- prologue: stage tile 0 (drained by syncthreads)
  stageK(0);
  stageV(0);
  __syncthreads();

  for (int kt = 0; kt < 16; kt++) {
    if (kt > 0) stageV(kt);  // in flight until BARRIER_B

    // S^T = K Q^T : A = K-frag (m=key), B = Q-frag (n=q)
    f32x4 s[8][2];
    for (int kb = 0; kb < 8; kb++) {
      bf16x8 kf[4];
      int a0 = (kb * 16 + l16) * 128 + ((quad ^ sw) << 3);
      for (int ki = 0; ki < 4; ki++)
        kf[ki] = *(const bf16x8*)&KP[a0 ^ (ki * 32)];
      __builtin_amdgcn_s_setprio(1);
      for (int qb = 0; qb < 2; qb++) {
        f32x4 a = {0.f, 0.f, 0.f, 0.f};
        for (int ki = 0; ki < 4; ki++)
          a = __builtin_amdgcn_mfma_f32_16x16x32_bf16(kf[ki], qf[qb][ki], a, 0, 0, 0);
        s[kb][qb] = a;
      }
      __builtin_amdgcn_s_setprio(0);
    }

    bar_sync();  // BARRIER_A: all waves' K reads done
    if (kt < 15) stageK(kt + 1);  // in flight until BARRIER_END

    // online softmax per q (q = qb*16 + l16); scores pre-scaled by C*log2e.
    // tree max + defer-max (THR=8 log2); exp fused with bf16 pack into u[8];
    // then permlane32_swap + xor16 exchange -> pf (PV B-fragments, in-reg).
    bf16x8 pf[2][4];
    float alch[2];
    for (int qb = 0; qb < 2; qb++) {
      float mk[8];
#pragma unroll
      for (int kb = 0; kb < 8; kb++)
        mk[kb] = fmaxf(fmaxf(s[kb][qb][0], s[kb][qb][1]),
                       fmaxf(s[kb][qb][2], s[kb][qb][3]));
      float mx = fmaxf(fmaxf(fmaxf(mk[0], mk[1]), fmaxf(mk[2], mk[3])),
                       fmaxf(fmaxf(mk[4], mk[5]), fmaxf(mk[6], mk[7])));
      mx = fmaxf(mx, __shfl_xor(mx, 16, 64));
      mx = fmaxf(mx, __shfl_xor(mx, 32, 64));
      float mn = m_[qb], al = 1.0f;
      if (!__all(mx <= m_[qb] + 8.0f)) {
        mn = fmaxf(m_[qb], mx);
        al = exp2f(m_[qb] - mn);
        m_[qb] = mn;
      }
      alch[qb] = al;
      uint2 u[8];
      float rs = 0.f;
#pragma unroll
      for (int kb = 0; kb < 8; kb++) {
        float p0 = exp2f(s[kb][qb][0] - mn), p1 = exp2f(s[kb][qb][1] - mn);
        float p2 = exp2f(s[kb][qb][2] - mn), p3 = exp2f(s[kb][qb][3] - mn);
        u[kb] = pack4(p0, p1, p2, p3);
        rs += (p0 + p1) + (p2 + p3);
      }
      rs += __shfl_xor(rs, 16, 64);
      rs += __shfl_xor(rs, 32, 64);
      l_[qb] = l_[qb] * al + rs;
      // exchange: pf[qb][ki] = P[q=l16-row][keys ki*32 + quad*8 + 0..7].
      // permlane32_swap(a,b): a' = [a_lo, b_lo], b' = [a_hi, b_hi].
      const bool qo = (quad & 1) != 0;
#pragma unroll
      for (int ki = 0; ki < 4; ki++) {
        u32x2 r1 = __builtin_amdgcn_permlane32_swap(u[2 * ki].x, u[2 * ki + 1].x, false, false);
        u32x2 r2 = __builtin_amdgcn_permlane32_swap(u[2 * ki].y, u[2 * ki + 1].y, false, false);
        uint32_t t1b = (uint32_t)__shfl_xor((int)r1[1], 16, 64);
        uint32_t t1a = (uint32_t)__shfl_xor((int)r1[0], 16, 64);
        uint32_t t2b = (uint32_t)__shfl_xor((int)r2[1], 16, 64);
        uint32_t t2a = (uint32_t)__shfl_xor((int)r2[0], 16, 64);
        uint4 d;
        d.x = qo ? t1b : (uint32_t)r1[0];
        d.y = qo ? t2b : (uint32_t)r2[0];
        d.z = qo ? (uint32_t)r1[1] : t1a;
        d.w = qo ? (uint32_t)r2[1] : t2a;
        pf[qb][ki] = *(bf16x8*)&d;
      }
    }
    // O-rescale (only when some row deferred past THR)
    if (alch[0] != 1.0f || alch[1] != 1.0f) {
#pragma unroll
      for (int db = 0; db < 8; db++) {
        o[db][0] *= alch[0];
        o[db][1] *= alch[1];
      }
    }

    // BARRIER_B: drain V_kt (8 older loads; the 8 K_{kt+1} stay flying)
    if (kt == 15) asm volatile("s_waitcnt vmcnt(0)" ::: "memory");
    else          asm volatile("s_waitcnt vmcnt(8)" ::: "memory");
    bar_sync();

    // O^T += V^T P^T : A = V-frag (m=d), B = pf (n=q, in registers)
    for (int db = 0; db < 8; db++) {
      bf16x8 vf[4];
      int a0 = (db * 16 + l16) * 128 + ((quad ^ sw) << 3);
      for (int ki = 0; ki < 4; ki++)
        vf[ki] = *(const bf16x8*)&Vls[a0 ^ (ki * 32)];
      __builtin_amdgcn_s_setprio(1);
      for (int qb = 0; qb < 2; qb++)
        for (int ki = 0; ki < 4; ki++)
          o[db][qb] = __builtin_amdgcn_mfma_f32_16x16x32_bf16(vf[ki], pf[qb][ki], o[db][qb], 0, 0, 0);
      __builtin_amdgcn_s_setprio(0);
    }

    // BARRIER_END: K_{kt+1} landed (covered by softmax+PV); Vls free after
    asm volatile("s_waitcnt vmcnt(0)" ::: "memory");
    bar_sync();
  }

  // epilogue: O^T/l -> LDS [q][d] packed b64 -> coalesced global store
  float inv[2] = {1.0f / l_[0], 1.0f / l_[1]};
  for (int qb = 0; qb < 2; qb++) {
    int rq = wave * 32 + qb * 16 + l16;
    for (int db = 0; db < 8; db++) {
      int ch = (db * 2 + (quad >> 1)) ^ sw;
      uint2 pv = pack4(o[db][qb][0] * inv[qb], o[db][qb][1] * inv[qb],
                       o[db][qb][2] * inv[qb], o[db][qb][3] * inv[qb]);
      *(uint2*)&KP[rq * 128 + (ch << 3) + (quad & 1) * 4] = pv;
    }
  }
  __syncthreads();
  u16* Ab = AO + (size_t)(b * 2048 + qt * 128) * 2048 + h * 128;
  for (int i = 0; i < 8; i++) {
    int row = i * 16 + (tid >> 4);
    int seg = tid & 15;
    int pc = seg ^ (row & 7);
    *(uint4*)(Ab + (size_t)row * 2048 + seg * 8) = *(const uint4*)&KP[row * 128 + pc * 8];
  }
}

// ---------------- launch ----------------
extern "C" void kernel_launch(void* const* d_in, const int* in_sizes, int n_in,
                              void* d_out, int out_size, void* d_ws, size_t ws_size,
                              hipStream_t stream) {
  (void)in_sizes; (void)n_in; (void)out_size; (void)ws_size;
  const float* x    = (const float*)d_in[0];
  const float* fcos = (const float*)d_in[1];
  const float* fsin = (const float*)d_in[2];
  const float* wq   = (const float*)d_in[3];
  const float* wk   = (const float*)d_in[4];
  const float* wv   = (const float*)d_in[5];
  const float* wo   = (const float*)d_in[6];

  char* w = (char*)d_ws;
  u16* xb  = (u16*)w;                               // 8192x2048 bf16, reused as attn_out
  u16* wT  = (u16*)(w + 33554432);                  // 3072x2048 bf16
  u16* woT = (u16*)(w + 33554432 + 12582912);       // 2048x2048 bf16
  u16* QKV = (u16*)(w + 33554432 + 12582912 + 8388608);            // 8192x3072 bf16
  u16* Vt  = (u16*)(w + 33554432 + 12582912 + 8388608 + 50331648); // 16x128x2048 bf16
  u16* AO  = xb;

  const float C = 0.08838834764831845f * 1.44269504088896340f;  // 1/sqrt(128)*log2(e)

  cast_x_kernel<<<16384, 256, 0, stream>>>((const float4*)x, (ushort4*)xb);
  wtrans_kernel<<<dim3(64, 64), dim3(32, 8), 0, stream>>>(wq, wT, 2048, 2048, C);
  wtrans_kernel<<<dim3(16, 64), dim3(32, 8), 0, stream>>>(wk, wT + (size_t)2048 * 2048, 2048, 512, 1.0f);
  wtrans_kernel<<<dim3(16, 64), dim3(32, 8), 0, stream>>>(wv, wT + (size_t)2560 * 2048, 2048, 512, 1.0f);
  wtrans_kernel<<<dim3(64, 64), dim3(32, 8), 0, stream>>>(wo, woT, 2048, 2048, 1.0f);

  gemm_bt_kernel<true><<<dim3(24, 64), 256, 0, stream>>>(xb, wT, QKV, 2048, 3072);
  rope_kernel<<<40960, 256, 0, stream>>>(QKV, fcos, fsin);
  vtrans_kernel<<<dim3(64, 4, 16), dim3(32, 8), 0, stream>>>(QKV, Vt);
  attn_kernel<<<dim3(16, 16, 4), 256, 0, stream>>>(QKV, Vt, AO);
  gemm_bt_kernel<false><<<dim3(16, 64), 256, 0, stream>>>(AO, woT, (float*)d_out, 2048, 2048);
}

// Round 10
// 545.806 us; speedup vs baseline: 1.0577x; 1.0577x over previous
//
#include <hip/hip_runtime.h>
#include <stdint.h>

// Attention_48945447306134 on MI355X.
//   GEMM1: QKV = xb @ [wq*C|wk|wv]^T  (wq pre-scaled by softmax_scale*log2e)
//     + FUSED epilogue: RoPE (f32, on-accumulator) for Q/K cols; V cols
//       written directly TRANSPOSED to Vt[b][hk][d][s] via LDS (rope_kernel
//       and vtrans_kernel eliminated).
//   Flash attention, TRANSPOSED algebra: S^T = K Q^T, O^T = V^T P^T
//     (unchanged from r9: in-reg P via permlane exchange, counted-vmcnt
//      K/V staging, defer-max, cvt_pk, setprio; linear block map).
//   GEMM2: out = attn @ woT (fp32 out)

typedef unsigned short u16;
typedef __bf16 bf16x8 __attribute__((ext_vector_type(8)));
typedef float  f32x4  __attribute__((ext_vector_type(4)));
typedef unsigned int u32x2 __attribute__((ext_vector_type(2)));

#define GLOAD16(gp, lp)                                                        \
  __builtin_amdgcn_global_load_lds(                                            \
      (const __attribute__((address_space(1))) void*)(gp),                     \
      (__attribute__((address_space(3))) void*)(lp), 16, 0, 0)

__device__ __forceinline__ u16 f2b(float f) {  // RNE f32->bf16
  union { float f; uint32_t u; } v; v.f = f;
  uint32_t r = v.u + 0x7FFFu + ((v.u >> 16) & 1u);
  return (u16)(r >> 16);
}
__device__ __forceinline__ float b2f(u16 h) {
  union { uint32_t u; float f; } v; v.u = ((uint32_t)h) << 16;
  return v.f;
}
// RNE pack via HW instruction
__device__ __forceinline__ uint2 pack4(float a, float b, float c, float d) {
  uint2 r;
  asm("v_cvt_pk_bf16_f32 %0, %1, %2" : "=v"(r.x) : "v"(a), "v"(b));
  asm("v_cvt_pk_bf16_f32 %0, %1, %2" : "=v"(r.y) : "v"(c), "v"(d));
  return r;
}

// block barrier that does NOT drain vmcnt (keeps staging loads in flight).
__device__ __forceinline__ void bar_sync() {
  asm volatile("s_waitcnt lgkmcnt(0)" ::: "memory");
  __builtin_amdgcn_s_barrier();
  asm volatile("" ::: "memory");
}

// ---------------- cast x -> bf16 ----------------
__global__ __launch_bounds__(256) void cast_x_kernel(const float4* __restrict__ in,
                                                     ushort4* __restrict__ out) {
  int i = blockIdx.x * 256 + threadIdx.x;
  float4 v = in[i];
  ushort4 o;
  o.x = f2b(v.x); o.y = f2b(v.y); o.z = f2b(v.z); o.w = f2b(v.w);
  out[i] = o;
}

// ------------- cast + transpose weight: W (KxN f32) -> WT (NxK bf16), * scale -------------
__global__ __launch_bounds__(256) void wtrans_kernel(const float* __restrict__ W,
                                                     u16* __restrict__ WT,
                                                     int K, int N, float scale) {
  __shared__ float t[32][33];
  int n0 = blockIdx.x * 32, k0 = blockIdx.y * 32;
  int tx = threadIdx.x, ty = threadIdx.y;  // 32 x 8
  for (int r = 0; r < 4; r++)
    t[ty + r * 8][tx] = W[(size_t)(k0 + ty + r * 8) * N + n0 + tx];
  __syncthreads();
  for (int r = 0; r < 4; r++)
    WT[(size_t)(n0 + ty + r * 8) * K + k0 + tx] = f2b(t[tx][ty + r * 8] * scale);
}

// ---------------- GEMM: C(MxN) = A(MxK) * BT(NxK)^T ----------------
// 128x128 tile, BK=32, 3-stage LDS pipeline in one SH arena (48 KB), counted
// vmcnt(4): oldest tile's loads land, newer 4 keep flying. Paired-row LDS
// layout (r>>1)*64 + (r&1)*32 + (q^((r>>1)&3))*8, staged via pre-swizzled
// global source. BF16OUT epilogue fusion:
//   n0 <  2560 : RoPE in f32 on the accumulator (pair = lane l16^1, one
//                shfl_xor; i = (col&127)>>1, s = row&2047), then bf16 store.
//   n0 >= 2560 : V block -- transpose via SH (rotation swizzle
//                phys = d*128 + ((s + 8*(d&15)) & 127)) and store to
//                Vt[(b*4+hk)*128 + d][s] with 16B-coalesced uint4 writes.
#define KSTEP(CUR, TT)                                                         \
  {                                                                            \
    if ((TT) + 1 < nt) asm volatile("s_waitcnt vmcnt(4)" ::: "memory");        \
    else               asm volatile("s_waitcnt vmcnt(0)" ::: "memory");        \
    bar_sync();                                                                \
    if ((TT) + 2 < nt) {                                                       \
      const size_t k0 = (size_t)((TT) + 2) * 32;                               \
      GLOAD16(Ag + k0, &SH[((CUR) + 2) % 3 * 4096 + ldst]);                    \
      GLOAD16(Ag + k0 + (size_t)16 * K, &SH[((CUR) + 2) % 3 * 4096 + ldst + 512]); \
      GLOAD16(Bg + k0, &SH[12288 + ((CUR) + 2) % 3 * 4096 + ldst]);            \
      GLOAD16(Bg + k0 + (size_t)16 * K, &SH[12288 + ((CUR) + 2) % 3 * 4096 + ldst + 512]); \
    }                                                                          \
    bf16x8 af[4], bf[4];                                                       \
    for (int i = 0; i < 4; i++)                                                \
      af[i] = *(const bf16x8*)&SH[(CUR) * 4096 + wm * 32 + i * 512 + lrd];     \
    for (int i = 0; i < 4; i++)                                                \
      bf[i] = *(const bf16x8*)&SH[12288 + (CUR) * 4096 + wn * 32 + i * 512 + lrd]; \
    __builtin_amdgcn_s_setprio(1);                                             \
    for (int mi = 0; mi < 4; mi++)                                             \
      for (int ni = 0; ni < 4; ni++)                                           \
        acc[mi][ni] = __builtin_amdgcn_mfma_f32_16x16x32_bf16(                 \
            af[mi], bf[ni], acc[mi][ni], 0, 0, 0);                             \
    __builtin_amdgcn_s_setprio(0);                                             \
  }

template <bool BF16OUT>
__global__ __launch_bounds__(256) void gemm_bt_kernel(const u16* __restrict__ A,
                                                      const u16* __restrict__ BT,
                                                      void* __restrict__ Cv,
                                                      int K, int N,
                                                      const float* __restrict__ cs,
                                                      const float* __restrict__ sn,
                                                      u16* __restrict__ Vt) {
  __shared__ u16 SH[24576];  // 3x4096 A bufs | 3x4096 B bufs (u16)
  const int tid = threadIdx.x;
  const int wave = tid >> 6, lane = tid & 63;
  const int quad = lane >> 4, l16 = lane & 15;
  const int wm = (wave >> 1) * 64, wn = (wave & 1) * 64;

  // XCD-aware bijective block swizzle (nwg % 8 == 0 for both call sites)
  const int nbx = gridDim.x;
  const int nwg = nbx * gridDim.y;
  const int d = blockIdx.x + blockIdx.y * nbx;
  const int w = (d & 7) * (nwg >> 3) + (d >> 3);
  const size_t m0 = (size_t)(w / nbx) * 128, n0 = (size_t)(w % nbx) * 128;

  f32x4 acc[4][4] = {};
  const int srow = wave * 32 + ((lane >> 3) << 1) + ((lane >> 2) & 1);
  const int tcol = ((lane & 3) ^ ((lane >> 3) & 3)) * 8;
  const u16* Ag = A + (m0 + srow) * (size_t)K + tcol;
  const u16* Bg = BT + (n0 + srow) * (size_t)K + tcol;
  const int ldst = wave * 1024;  // u16; per-instr +512 (16 rows)
  const int lrd = (l16 >> 1) * 64 + (l16 & 1) * 32 +
                  ((quad ^ ((l16 >> 1) & 3)) << 3);
  const int nt = K >> 5;  // must be ≡ 1 (mod 3); 64 at both call sites

  // prologue: stage tiles 0 and 1
  GLOAD16(Ag, &SH[ldst]);
  GLOAD16(Ag + (size_t)16 * K, &SH[ldst + 512]);
  GLOAD16(Bg, &SH[12288 + ldst]);
  GLOAD16(Bg + (size_t)16 * K, &SH[12288 + ldst + 512]);
  GLOAD16(Ag + 32, &SH[4096 + ldst]);
  GLOAD16(Ag + 32 + (size_t)16 * K, &SH[4096 + ldst + 512]);
  GLOAD16(Bg + 32, &SH[12288 + 4096 + ldst]);
  GLOAD16(Bg + 32 + (size_t)16 * K, &SH[12288 + 4096 + ldst + 512]);

  int t = 0;
  for (; t + 4 < nt; t += 3) {
    KSTEP(0, t);
    KSTEP(1, t + 1);
    KSTEP(2, t + 2);
  }
  // tail for nt % 3 == 1 (t == nt-4 here)
  KSTEP(0, t);
  KSTEP(1, t + 1);
  KSTEP(2, t + 2);
  KSTEP(0, t + 3);

  if constexpr (BF16OUT) {
    if (n0 >= 2560) {
      // ---- V block: acc -> SH transposed ([d][s], rotated) -> Vt
      bar_sync();  // all waves' frag reads done before SH reuse
      for (int mi = 0; mi < 4; mi++)
        for (int ni = 0; ni < 4; ni++) {
          int dl = wn + ni * 16 + l16;        // col within tile = d
          int sl = wm + mi * 16 + quad * 4;   // row within tile = s
          uint2 pv = pack4(acc[mi][ni][0], acc[mi][ni][1],
                           acc[mi][ni][2], acc[mi][ni][3]);
          int rot = 8 * (dl & 15);
          *(uint32_t*)&SH[dl * 128 + ((sl + rot) & 127)] = pv.x;
          *(uint32_t*)&SH[dl * 128 + ((sl + 2 + rot) & 127)] = pv.y;
        }
      __syncthreads();
      const int bb = (int)(m0 >> 11), s0v = (int)(m0 & 2047);
      const int hk = (int)((n0 - 2560) >> 7);
      u16* dst0 = Vt + ((size_t)(bb * 4 + hk) * 128) * 2048 + s0v;
      for (int i = 0; i < 8; i++) {
        int dd = i * 16 + (tid >> 4);
        int seg = tid & 15;
        int src = dd * 128 + ((seg + (dd & 15)) & 15) * 8;
        *(uint4*)(dst0 + (size_t)dd * 2048 + seg * 8) = *(const uint4*)&SH[src];
      }
    } else {
      // ---- Q/K block: RoPE in f32 on accumulator, then bf16 store.
      // pair (2i,2i+1) = adjacent cols = lanes l16^1 (col parity = l16
      // parity since n0,wn,ni*16 all even); rotation commutes with the
      // pre-applied Q scale C.
      for (int mi = 0; mi < 4; mi++)
        for (int ni = 0; ni < 4; ni++) {
          int col = (int)n0 + wn + ni * 16 + l16;
          int ii = (col & 127) >> 1;
          bool odd = (col & 1) != 0;
          for (int r = 0; r < 4; r++) {
            int row = (int)m0 + wm + mi * 16 + quad * 4 + r;
            int s = row & 2047;
            float v = acc[mi][ni][r];
            float pv = __shfl_xor(v, 1, 64);
            float c_ = cs[(size_t)s * 64 + ii];
            float s_ = sn[(size_t)s * 64 + ii];
            float out = odd ? (pv * s_ + v * c_) : (v * c_ - pv * s_);
            ((u16*)Cv)[(size_t)row * N + col] = f2b(out);
          }
        }
    }
  } else {
    for (int mi = 0; mi < 4; mi++)
      for (int ni = 0; ni < 4; ni++)
        for (int r = 0; r < 4; r++) {
          size_t row = m0 + wm + mi * 16 + quad * 4 + r;
          size_t col = n0 + wn + ni * 16 + l16;
          ((float*)Cv)[row * N + col] = acc[mi][ni][r];
        }
  }
}

// ---------------- flash attention (transposed algebra, P in registers) ------
// grid (qt=16, h=16, b=4), 256 threads = 4 waves, 32 q-rows/wave. Linear
// block mapping (XCD swizzle reverted -- r8 A/B showed regression).
// Per iter kt:
//   [top] if kt>0: issue V_kt gload_lds
//   QK^T -> BARRIER_A -> issue K_{kt+1} gload_lds
//   softmax + exp->bf16 pack -> permlane32_swap/xor16 exchange -> pf (in-reg)
//   BARRIER_B: vmcnt(8) (drain V_kt, keep K flying)
//   PV -> BARRIER_END: vmcnt(0)
__global__ __launch_bounds__(256, 2) void attn_kernel(const u16* __restrict__ QKV,
                                                      const u16* __restrict__ Vt,
                                                      u16* __restrict__ AO) {
  __shared__ u16 KP[128 * 128];
  __shared__ u16 Vls[128 * 128];
  const int tid = threadIdx.x;
  const int wave = tid >> 6, lane = tid & 63;
  const int quad = lane >> 4, l16 = lane & 15;
  const int qt = blockIdx.x, h = blockIdx.y, b = blockIdx.z;
  const int hk = h >> 2;
  const int sw = l16 & 7;  // row-dependent swizzle key for this lane's rows

  // Q fragments (B-operand: n=q=l16, k=d)
  bf16x8 qf[2][4];
  {
    const u16* Qb = QKV + (size_t)(b * 2048 + qt * 128 + wave * 32) * 3072 + h * 128;
    for (int qb = 0; qb < 2; qb++)
      for (int ki = 0; ki < 4; ki++)
        qf[qb][ki] = *(const bf16x8*)(Qb + (size_t)(qb * 16 + l16) * 3072 + ki * 32 + quad * 8);
  }
  f32x4 o[8][2] = {};            // O^T: [db][qb], col=q(l16), row=d(quad*4+r)
  float m_[2] = {-1e30f, -1e30f}, l_[2] = {0.f, 0.f};

  const u16* Kg0 = QKV + 2048 + hk * 128;
  const u16* Vg0 = Vt + (size_t)((b * 4 + hk) * 128) * 2048;
  const int r4 = lane >> 4, c16 = lane & 15;

  // staging: tile t of K (rows=key, cols=d) / V (rows=d, cols=key), 8 chunks/wave
  auto stageK = [&](int t) {
    const u16* Kg = Kg0 + (size_t)(b * 2048 + t * 128) * 3072;
    for (int i = 0; i < 8; i++) {
      int grp = i * 4 + wave;
      int row = grp * 4 + r4;
      int ch = c16 ^ (row & 7);
      GLOAD16(Kg + (size_t)row * 3072 + ch * 8, &KP[grp * 512]);
    }
  };
  auto stageV = [&](int t) {
    const u16* Vg = Vg0 + t * 128;
    for (int i = 0; i < 8; i++) {
      int grp = i * 4 + wave;
      int row = grp * 4 + r4;
      int ch = c16 ^ (row & 7);
      GLOAD16(Vg + (size_t)row * 2048 + ch * 8, &Vls[grp * 512]);
    }
  };

  // ---- prologue: stage tile 0 (drained by syncthreads)
  stageK(0);
  stageV(0);
  __syncthreads();

  for (int kt = 0; kt < 16; kt++) {
    if (kt > 0) stageV(kt);  // in flight until BARRIER_B

    // S^T = K Q^T : A = K-frag (m=key), B = Q-frag (n=q)
    f32x4 s[8][2];
    for (int kb = 0; kb < 8; kb++) {
      bf16x8 kf[4];
      int a0 = (kb * 16 + l16) * 128 + ((quad ^ sw) << 3);
      for (int ki = 0; ki < 4; ki++)
        kf[ki] = *(const bf16x8*)&KP[a0 ^ (ki * 32)];
      __builtin_amdgcn_s_setprio(1);
      for (int qb = 0; qb < 2; qb++) {
        f32x4 a = {0.f, 0.f, 0.f, 0.f};
        for (int ki = 0; ki < 4; ki++)
          a = __builtin_amdgcn_mfma_f32_16x16x32_bf16(kf[ki], qf[qb][ki], a, 0, 0, 0);
        s[kb][qb] = a;
      }
      __builtin_amdgcn_s_setprio(0);
    }

    bar_sync();  // BARRIER_A: all waves' K reads done
    if (kt < 15) stageK(kt + 1);  // in flight until BARRIER_END

    // online softmax per q (q = qb*16 + l16); scores pre-scaled by C*log2e.
    // tree max + defer-max (THR=8 log2); exp fused with bf16 pack into u[8];
    // then permlane32_swap + xor16 exchange -> pf (PV B-fragments, in-reg).
    bf16x8 pf[2][4];
    float alch[2];
    for (int qb = 0; qb < 2; qb++) {
      float mk[8];
#pragma unroll
      for (int kb = 0; kb < 8; kb++)
        mk[kb] = fmaxf(fmaxf(s[kb][qb][0], s[kb][qb][1]),
                       fmaxf(s[kb][qb][2], s[kb][qb][3]));
      float mx = fmaxf(fmaxf(fmaxf(mk[0], mk[1]), fmaxf(mk[2], mk[3])),
                       fmaxf(fmaxf(mk[4], mk[5]), fmaxf(mk[6], mk[7])));
      mx = fmaxf(mx, __shfl_xor(mx, 16, 64));
      mx = fmaxf(mx, __shfl_xor(mx, 32, 64));
      float mn = m_[qb], al = 1.0f;
      if (!__all(mx <= m_[qb] + 8.0f)) {
        mn = fmaxf(m_[qb], mx);
        al = exp2f(m_[qb] - mn);
        m_[qb] = mn;
      }
      alch[qb] = al;
      uint2 u[8];
      float rs = 0.f;
#pragma unroll
      for (int kb = 0; kb < 8; kb++) {
        float p0 = exp2f(s[kb][qb][0] - mn), p1 = exp2f(s[kb][qb][1] - mn);
        float p2 = exp2f(s[kb][qb][2] - mn), p3 = exp2f(s[kb][qb][3] - mn);
        u[kb] = pack4(p0, p1, p2, p3);
        rs += (p0 + p1) + (p2 + p3);
      }
      rs += __shfl_xor(rs, 16, 64);
      rs += __shfl_xor(rs, 32, 64);
      l_[qb] = l_[qb] * al + rs;
      // exchange: pf[qb][ki] = P[q=l16-row][keys ki*32 + quad*8 + 0..7].
      // permlane32_swap(a,b): a' = [a_lo, b_lo], b' = [a_hi, b_hi].
      const bool qo = (quad & 1) != 0;
#pragma unroll
      for (int ki = 0; ki < 4; ki++) {
        u32x2 r1 = __builtin_amdgcn_permlane32_swap(u[2 * ki].x, u[2 * ki + 1].x, false, false);
        u32x2 r2 = __builtin_amdgcn_permlane32_swap(u[2 * ki].y, u[2 * ki + 1].y, false, false);
        uint32_t t1b = (uint32_t)__shfl_xor((int)r1[1], 16, 64);
        uint32_t t1a = (uint32_t)__shfl_xor((int)r1[0], 16, 64);
        uint32_t t2b = (uint32_t)__shfl_xor((int)r2[1], 16, 64);
        uint32_t t2a = (uint32_t)__shfl_xor((int)r2[0], 16, 64);
        uint4 d;
        d.x = qo ? t1b : (uint32_t)r1[0];
        d.y = qo ? t2b : (uint32_t)r2[0];
        d.z = qo ? (uint32_t)r1[1] : t1a;
        d.w = qo ? (uint32_t)r2[1] : t2a;
        pf[qb][ki] = *(bf16x8*)&d;
      }
    }
    // O-rescale (only when some row deferred past THR)
    if (alch[0] != 1.0f || alch[1] != 1.0f) {
#pragma unroll
      for (int db = 0; db < 8; db++) {
        o[db][0] *= alch[0];
        o[db][1] *= alch[1];
      }
    }

    // BARRIER_B: drain V_kt (8 older loads; the 8 K_{kt+1} stay flying)
    if (kt == 15) asm volatile("s_waitcnt vmcnt(0)" ::: "memory");
    else          asm volatile("s_waitcnt vmcnt(8)" ::: "memory");
    bar_sync();

    // O^T += V^T P^T : A = V-frag (m=d), B = pf (n=q, in registers)
    for (int db = 0; db < 8; db++) {
      bf16x8 vf[4];
      int a0 = (db * 16 + l16) * 128 + ((quad ^ sw) << 3);
      for (int ki = 0; ki < 4; ki++)
        vf[ki] = *(const bf16x8*)&Vls[a0 ^ (ki * 32)];
      __builtin_amdgcn_s_setprio(1);
      for (int qb = 0; qb < 2; qb++)
        for (int ki = 0; ki < 4; ki++)
          o[db][qb] = __builtin_amdgcn_mfma_f32_16x16x32_bf16(vf[ki], pf[qb][ki], o[db][qb], 0, 0, 0);
      __builtin_amdgcn_s_setprio(0);
    }

    // BARRIER_END: K_{kt+1} landed (covered by softmax+PV); Vls free after
    asm volatile("s_waitcnt vmcnt(0)" ::: "memory");
    bar_sync();
  }

  // epilogue: O^T/l -> LDS [q][d] packed b64 -> coalesced global store
  float inv[2] = {1.0f / l_[0], 1.0f / l_[1]};
  for (int qb = 0; qb < 2; qb++) {
    int rq = wave * 32 + qb * 16 + l16;
    for (int db = 0; db < 8; db++) {
      int ch = (db * 2 + (quad >> 1)) ^ sw;
      uint2 pv = pack4(o[db][qb][0] * inv[qb], o[db][qb][1] * inv[qb],
                       o[db][qb][2] * inv[qb], o[db][qb][3] * inv[qb]);
      *(uint2*)&KP[rq * 128 + (ch << 3) + (quad & 1) * 4] = pv;
    }
  }
  __syncthreads();
  u16* Ab = AO + (size_t)(b * 2048 + qt * 128) * 2048 + h * 128;
  for (int i = 0; i < 8; i++) {
    int row = i * 16 + (tid >> 4);
    int seg = tid & 15;
    int pc = seg ^ (row & 7);
    *(uint4*)(Ab + (size_t)row * 2048 + seg * 8) = *(const uint4*)&KP[row * 128 + pc * 8];
  }
}

// ---------------- launch ----------------
extern "C" void kernel_launch(void* const* d_in, const int* in_sizes, int n_in,
                              void* d_out, int out_size, void* d_ws, size_t ws_size,
                              hipStream_t stream) {
  (void)in_sizes; (void)n_in; (void)out_size; (void)ws_size;
  const float* x    = (const float*)d_in[0];
  const float* fcos = (const float*)d_in[1];
  const float* fsin = (const float*)d_in[2];
  const float* wq   = (const float*)d_in[3];
  const float* wk   = (const float*)d_in[4];
  const float* wv   = (const float*)d_in[5];
  const float* wo   = (const float*)d_in[6];

  char* w = (char*)d_ws;
  u16* xb  = (u16*)w;                               // 8192x2048 bf16, reused as attn_out
  u16* wT  = (u16*)(w + 33554432);                  // 3072x2048 bf16
  u16* woT = (u16*)(w + 33554432 + 12582912);       // 2048x2048 bf16
  u16* QKV = (u16*)(w + 33554432 + 12582912 + 8388608);            // 8192x3072 bf16
  u16* Vt  = (u16*)(w + 33554432 + 12582912 + 8388608 + 50331648); // 16x128x2048 bf16
  u16* AO  = xb;

  const float C = 0.08838834764831845f * 1.44269504088896340f;  // 1/sqrt(128)*log2(e)

  cast_x_kernel<<<16384, 256, 0, stream>>>((const float4*)x, (ushort4*)xb);
  wtrans_kernel<<<dim3(64, 64), dim3(32, 8), 0, stream>>>(wq, wT, 2048, 2048, C);
  wtrans_kernel<<<dim3(16, 64), dim3(32, 8), 0, stream>>>(wk, wT + (size_t)2048 * 2048, 2048, 512, 1.0f);
  wtrans_kernel<<<dim3(16, 64), dim3(32, 8), 0, stream>>>(wv, wT + (size_t)2560 * 2048, 2048, 512, 1.0f);
  wtrans_kernel<<<dim3(64, 64), dim3(32, 8), 0, stream>>>(wo, woT, 2048, 2048, 1.0f);

  // GEMM1 with fused RoPE + V-transpose (rope_kernel/vtrans_kernel eliminated)
  gemm_bt_kernel<true><<<dim3(24, 64), 256, 0, stream>>>(xb, wT, QKV, 2048, 3072,
                                                         fcos, fsin, Vt);
  attn_kernel<<<dim3(16, 16, 4), 256, 0, stream>>>(QKV, Vt, AO);
  gemm_bt_kernel<false><<<dim3(16, 64), 256, 0, stream>>>(AO, woT, (float*)d_out, 2048, 2048,
                                                          nullptr, nullptr, nullptr);
}